// Round 2
// baseline (106.034 us; speedup 1.0000x reference)
//
#include <hip/hip_runtime.h>
#include <hip/hip_bf16.h>
#include <stdint.h>

#define BSZ 384
#define DD  256
#define NEG_BIG -3.0e38f

// ---------------- threefry2x32, key = (0, 42) = jax.random.key(42) -----------
__device__ __forceinline__ void threefry_0_42(uint32_t c0, uint32_t c1,
                                              uint32_t& o0, uint32_t& o1) {
    const uint32_t k0 = 0u;
    const uint32_t k1 = 42u;
    const uint32_t k2 = 0u ^ 42u ^ 0x1BD11BDAu;
    uint32_t x0 = c0 + k0;
    uint32_t x1 = c1 + k1;
#define TF_RND(R) { x0 += x1; x1 = (x1 << (R)) | (x1 >> (32 - (R))); x1 ^= x0; }
    TF_RND(13) TF_RND(15) TF_RND(26) TF_RND(6)
    x0 += k1; x1 += k2 + 1u;
    TF_RND(17) TF_RND(29) TF_RND(16) TF_RND(24)
    x0 += k2; x1 += k0 + 2u;
    TF_RND(13) TF_RND(15) TF_RND(26) TF_RND(6)
    x0 += k0; x1 += k1 + 3u;
    TF_RND(17) TF_RND(29) TF_RND(16) TF_RND(24)
    x0 += k1; x1 += k2 + 4u;
    TF_RND(13) TF_RND(15) TF_RND(26) TF_RND(6)
    x0 += k2; x1 += k0 + 5u;
#undef TF_RND
    o0 = x0; o1 = x1;
}

// gumbel[idx] as jax.random.gumbel(key(42), (B,B,B), f32) under
// jax_threefry_partitionable=True (default since JAX 0.4.36):
//   counter = uint64 idx -> cipher(hi32, lo32) = cipher(0, idx) for idx < 2^32
//   32-bit output = bits1 ^ bits2 (XOR fold of the 2x32 cipher block)
__device__ __forceinline__ float gumbel_at(uint32_t idx) {
    uint32_t r0, r1;
    threefry_0_42(0u, idx, r0, r1);
    uint32_t bits = r0 ^ r1;
    uint32_t mant = bits >> 9;
    float f = __uint_as_float(mant | 0x3F800000u) - 1.0f; // exact in [0,1)
    float u = (mant == 0u) ? 1.17549435e-38f : f;         // minval = f32 tiny
    return -logf(-logf(u));
}

// ---------------- pairwise distances: 16x16 tiles --------------------------
__global__ __launch_bounds__(256) void dist_kernel(const float* __restrict__ F,
                                                   float* __restrict__ dist) {
    __shared__ float As[16][DD + 4];
    __shared__ float Bs[16][DD + 4];
    const int i0 = blockIdx.y * 16;
    const int j0 = blockIdx.x * 16;
    const int tid = threadIdx.x;

    // stage 16 rows of A and B (16 * 64 float4 each; 4 per thread), coalesced
    for (int t = tid; t < 16 * 64; t += 256) {
        const int r = t >> 6;
        const int c = (t & 63) << 2;
        float4 a = *(const float4*)&F[(i0 + r) * DD + c];
        float4 b = *(const float4*)&F[(j0 + r) * DD + c];
        *(float4*)&As[r][c] = a;
        *(float4*)&Bs[r][c] = b;
    }
    __syncthreads();

    const int tx = tid & 15;  // j within tile
    const int ty = tid >> 4;  // i within tile
    float a0 = 0.f, a1 = 0.f, a2 = 0.f, a3 = 0.f;
#pragma unroll 8
    for (int d = 0; d < DD; d += 4) {
        float4 av = *(const float4*)&As[ty][d];
        float4 bv = *(const float4*)&Bs[tx][d];
        float d0 = av.x - bv.x;
        float d1 = av.y - bv.y;
        float d2 = av.z - bv.z;
        float d3 = av.w - bv.w;
        a0 = fmaf(d0, d0, a0);
        a1 = fmaf(d1, d1, a1);
        a2 = fmaf(d2, d2, a2);
        a3 = fmaf(d3, d3, a3);
    }
    float s = (a0 + a1) + (a2 + a3);
    s = fmaxf(s, 1e-11f);
    dist[(i0 + ty) * BSZ + (j0 + tx)] = sqrtf(s);
}

// ---------------- semi-hard mining + loss accumulation ---------------------
__global__ __launch_bounds__(BSZ) void mine_kernel(const float* __restrict__ dist,
                                                   const int* __restrict__ labels,
                                                   const int* __restrict__ epochp,
                                                   float* __restrict__ total_out,
                                                   unsigned int* __restrict__ count_out) {
    __shared__ float row[BSZ];
    __shared__ int   slab[BSZ];
    __shared__ float sv[6];
    __shared__ int   si[6];

    const int i   = blockIdx.x;
    const int tid = threadIdx.x;  // == candidate index k
    const int lab_i = labels[i];
    const int epoch = *epochp;
    const bool semisel = (epoch > 3);

    const float dk = dist[i * BSZ + tid];
    row[tid]  = dk;
    const int lk = labels[tid];
    slab[tid] = lk;
    const bool neg = (lk != lab_i);
    const float base = semisel ? -logf(dk) : 0.0f;
    __syncthreads();

    float    t_total = 0.0f;
    unsigned t_count = 0u;
    const uint32_t ibase = (uint32_t)i * (uint32_t)BSZ;

    for (int j = i + 1; j < BSZ; ++j) {
        if (slab[j] != lab_i) continue;  // block-uniform

        const float d_pos = row[j];
        const float hi    = d_pos + 0.2f;

        float val = NEG_BIG;
        const bool cand = neg && (!semisel || (dk > d_pos && dk < hi));
        if (cand) {
            const uint32_t idx = (ibase + (uint32_t)j) * (uint32_t)BSZ + (uint32_t)tid;
            val = base + gumbel_at(idx);
        }

        // wave-level argmax (val desc, idx asc to match jnp.argmax first-max)
        float v = val;
        int   kk = tid;
#pragma unroll
        for (int off = 32; off > 0; off >>= 1) {
            float ov = __shfl_down(v, off, 64);
            int   oi = __shfl_down(kk, off, 64);
            if (ov > v || (ov == v && oi < kk)) { v = ov; kk = oi; }
        }
        const int w = tid >> 6;
        if ((tid & 63) == 0) { sv[w] = v; si[w] = kk; }
        __syncthreads();
        if (tid == 0) {
            float bv = sv[0];
            int   bi = si[0];
#pragma unroll
            for (int q = 1; q < 6; ++q) {
                if (sv[q] > bv || (sv[q] == bv && si[q] < bi)) { bv = sv[q]; bi = si[q]; }
            }
            if (bv > -1.0e38f) {  // has_neg: at least one candidate existed
                float pp = d_pos - row[bi] + 0.2f;
                t_total += fmaxf(pp, 0.0f);
                t_count += 1u;
            }
        }
        __syncthreads();  // protect sv/si reuse next iteration
    }

    if (tid == 0 && t_count > 0u) {
        atomicAdd(total_out, t_total);
        atomicAdd(count_out, t_count);
    }
}

__global__ void finalize_kernel(const float* __restrict__ total,
                                const unsigned int* __restrict__ count,
                                float* __restrict__ out) {
    const unsigned c = *count;
    out[0] = (c > 0u) ? (total[0] / (float)c) : 0.0f;
}

extern "C" void kernel_launch(void* const* d_in, const int* in_sizes, int n_in,
                              void* d_out, int out_size, void* d_ws, size_t ws_size,
                              hipStream_t stream) {
    const float* F      = (const float*)d_in[0];
    const int*   labels = (const int*)d_in[1];
    const int*   epoch  = (const int*)d_in[2];
    float*       out    = (float*)d_out;

    const size_t dist_bytes = (size_t)BSZ * BSZ * sizeof(float);
    if (ws_size < dist_bytes + 16) return;  // safety: never write OOB

    float*        dist  = (float*)d_ws;
    float*        total = (float*)((char*)d_ws + dist_bytes);
    unsigned int* count = (unsigned int*)(total + 1);

    hipMemsetAsync(total, 0, 2 * sizeof(float), stream);  // zero accum (ws is poisoned)

    dist_kernel<<<dim3(BSZ / 16, BSZ / 16), 256, 0, stream>>>(F, dist);
    mine_kernel<<<BSZ, BSZ, 0, stream>>>(dist, labels, epoch, total, count);
    finalize_kernel<<<1, 1, 0, stream>>>(total, count, out);
}

// Round 3
// 87.564 us; speedup vs baseline: 1.2109x; 1.2109x over previous
//
#include <hip/hip_runtime.h>
#include <hip/hip_bf16.h>
#include <stdint.h>

#define BSZ 384
#define DD  256
#define NWAVES 6
#define NEG_BIG -3.0e38f

// ---------------- threefry2x32, key = (0, 42) = jax.random.key(42) -----------
__device__ __forceinline__ void threefry_0_42(uint32_t c0, uint32_t c1,
                                              uint32_t& o0, uint32_t& o1) {
    const uint32_t k0 = 0u;
    const uint32_t k1 = 42u;
    const uint32_t k2 = 0u ^ 42u ^ 0x1BD11BDAu;
    uint32_t x0 = c0 + k0;
    uint32_t x1 = c1 + k1;
#define TF_RND(R) { x0 += x1; x1 = (x1 << (R)) | (x1 >> (32 - (R))); x1 ^= x0; }
    TF_RND(13) TF_RND(15) TF_RND(26) TF_RND(6)
    x0 += k1; x1 += k2 + 1u;
    TF_RND(17) TF_RND(29) TF_RND(16) TF_RND(24)
    x0 += k2; x1 += k0 + 2u;
    TF_RND(13) TF_RND(15) TF_RND(26) TF_RND(6)
    x0 += k0; x1 += k1 + 3u;
    TF_RND(17) TF_RND(29) TF_RND(16) TF_RND(24)
    x0 += k1; x1 += k2 + 4u;
    TF_RND(13) TF_RND(15) TF_RND(26) TF_RND(6)
    x0 += k2; x1 += k0 + 5u;
#undef TF_RND
    o0 = x0; o1 = x1;
}

// gumbel[idx] as jax.random.gumbel(key(42), (B,B,B), f32) under
// jax_threefry_partitionable=True: cipher(0, idx), output = r0 ^ r1.
// (Verified bit-exact vs reference in round 2: absmax 0.0.)
__device__ __forceinline__ float gumbel_at(uint32_t idx) {
    uint32_t r0, r1;
    threefry_0_42(0u, idx, r0, r1);
    uint32_t bits = r0 ^ r1;
    uint32_t mant = bits >> 9;
    float f = __uint_as_float(mant | 0x3F800000u) - 1.0f; // exact in [0,1)
    float u = (mant == 0u) ? 1.17549435e-38f : f;         // minval = f32 tiny
    return -logf(-logf(u));
}

// One block per anchor i: compute dist row i from F directly, build compact
// positive list, wave-per-pair semi-hard mining (no barriers in mining loop),
// last-done-block epilogue writes the final mean.
__global__ __launch_bounds__(BSZ) void fused_kernel(const float* __restrict__ F,
                                                    const int* __restrict__ labels,
                                                    const int* __restrict__ epochp,
                                                    float* __restrict__ total,
                                                    unsigned int* __restrict__ count,
                                                    unsigned int* __restrict__ done,
                                                    float* __restrict__ out) {
    __shared__ float    Fi[DD];       // anchor feature row
    __shared__ float    row[BSZ];     // dist(i, k)
    __shared__ float    nlog[BSZ];    // -log(dist(i,k)) (0 if epoch<=3)
    __shared__ int      slab[BSZ];    // labels
    __shared__ int      plist[BSZ];   // compact positive-j list
    __shared__ int      npos;
    __shared__ float    wtot[NWAVES];
    __shared__ unsigned wcnt[NWAVES];

    const int i    = blockIdx.x;
    const int tid  = threadIdx.x;
    const int wave = tid >> 6;
    const int lane = tid & 63;

    slab[tid] = labels[tid];
    if (tid < DD / 4)
        ((float4*)Fi)[tid] = ((const float4*)(F + (size_t)i * DD))[tid];
    if (tid == 0) npos = 0;
    __syncthreads();

    const int lab_i = slab[i];
    if (tid > i && slab[tid] == lab_i)
        plist[atomicAdd(&npos, 1)] = tid;   // order irrelevant: pairs are independent
    const int  epoch   = *epochp;
    const bool semisel = (epoch > 3);
    __syncthreads();

    const int np = npos;
    float    t_total = 0.0f;
    unsigned t_count = 0u;

    if (np > 0) {
        // dist(i, tid): F[i] from LDS (broadcast), F[tid] via float4 gather
        // (F = 384 KB, L1/L2-resident; 8 consecutive d4 hit the same 128B line).
        // Accumulation order identical to the validated round-2 dist_kernel.
        const float4* frow = (const float4*)(F + (size_t)tid * DD);
        float a0 = 0.f, a1 = 0.f, a2 = 0.f, a3 = 0.f;
#pragma unroll 8
        for (int d4 = 0; d4 < DD / 4; ++d4) {
            float4 b = frow[d4];
            float4 a = ((const float4*)Fi)[d4];
            float d0 = a.x - b.x;
            float d1 = a.y - b.y;
            float d2 = a.z - b.z;
            float d3 = a.w - b.w;
            a0 = fmaf(d0, d0, a0);
            a1 = fmaf(d1, d1, a1);
            a2 = fmaf(d2, d2, a2);
            a3 = fmaf(d3, d3, a3);
        }
        float s  = (a0 + a1) + (a2 + a3);
        float dk = sqrtf(fmaxf(s, 1e-11f));
        row[tid]  = dk;
        nlog[tid] = semisel ? -logf(dk) : 0.0f;
        __syncthreads();

        // wave w owns positive pairs p = w, w+6, ... — no barriers below
        for (int p = wave; p < np; p += NWAVES) {
            const int   j     = plist[p];
            const float d_pos = row[j];
            const float hi    = d_pos + 0.2f;
            float v  = NEG_BIG;
            int   kk = 0;
#pragma unroll
            for (int c = 0; c < BSZ / 64; ++c) {
                const int   k   = c * 64 + lane;
                const float dkk = row[k];
                const bool cand = (slab[k] != lab_i) &&
                                  (!semisel || (dkk > d_pos && dkk < hi));
                if (__any(cand)) {          // whole-chunk skip when no candidates
                    if (cand) {
                        const uint32_t idx = (uint32_t)(i * BSZ + j) * (uint32_t)BSZ
                                             + (uint32_t)k;
                        float val = nlog[k] + gumbel_at(idx);
                        if (val > v) { v = val; kk = k; }  // strict > keeps first max
                    }
                }
            }
            // wave argmax (val desc, idx asc — matches jnp.argmax first-max)
#pragma unroll
            for (int off = 32; off; off >>= 1) {
                float ov = __shfl_down(v, off, 64);
                int   oi = __shfl_down(kk, off, 64);
                if (ov > v || (ov == v && oi < kk)) { v = ov; kk = oi; }
            }
            if (lane == 0 && v > -1.0e38f) {  // has_neg
                t_total += fmaxf(d_pos - row[kk] + 0.2f, 0.0f);
                t_count += 1u;
            }
        }
    }

    if (lane == 0) { wtot[wave] = t_total; wcnt[wave] = t_count; }
    __syncthreads();
    if (tid == 0) {
        float    tt = 0.0f;
        unsigned cc = 0u;
#pragma unroll
        for (int q = 0; q < NWAVES; ++q) { tt += wtot[q]; cc += wcnt[q]; }
        if (cc) {
            atomicAdd(total, tt);
            atomicAdd(count, cc);
        }
        __threadfence();  // make our adds visible before signaling done
        const unsigned prev = atomicAdd(done, 1u);
        if (prev == (unsigned)gridDim.x - 1u) {
            // all blocks signaled; read accumulators via device-scope atomics
            const float    T = atomicAdd(total, 0.0f);
            const unsigned C = atomicAdd(count, 0u);
            out[0] = (C > 0u) ? (T / (float)C) : 0.0f;
        }
    }
}

extern "C" void kernel_launch(void* const* d_in, const int* in_sizes, int n_in,
                              void* d_out, int out_size, void* d_ws, size_t ws_size,
                              hipStream_t stream) {
    const float* F      = (const float*)d_in[0];
    const int*   labels = (const int*)d_in[1];
    const int*   epoch  = (const int*)d_in[2];
    float*       out    = (float*)d_out;

    if (ws_size < 12) return;  // safety
    float*        total = (float*)d_ws;
    unsigned int* count = (unsigned int*)d_ws + 1;
    unsigned int* done  = (unsigned int*)d_ws + 2;

    hipMemsetAsync(d_ws, 0, 12, stream);  // zero accumulators (ws is poisoned)
    fused_kernel<<<BSZ, BSZ, 0, stream>>>(F, labels, epoch, total, count, done, out);
}